// Round 12
// baseline (1278.526 us; speedup 1.0000x reference)
//
#include <hip/hip_runtime.h>

#define DIM 512
#define N_ROWS 16384
#define K_CODES 8192
#define BK 32
#define TM 256
#define TN 128
#define NG (K_CODES / TN)               // 64 code groups
#define OUT_ELEMS (N_ROWS * DIM)        // 8388608
#define MARGIN 0.125f
#define CAP_ITEMS 262144                // (row,group) rescan items; ~3100 expected
#define NT (DIM / BK)                   // 16 K-steps

typedef _Float16 f16;
typedef _Float16 f16x8 __attribute__((ext_vector_type(8)));
typedef float f32x4 __attribute__((ext_vector_type(4)));

// monotone float->uint map: min on packed == (min dist, then min idx)
__device__ __forceinline__ unsigned long long pack_di(float d, int i) {
  unsigned u = __float_as_uint(d);
  u = (u & 0x80000000u) ? ~u : (u | 0x80000000u);
  return ((unsigned long long)u << 32) | (unsigned)i;
}

// ---------------- kernel 0: fp32 -> fp16 cast (x) ----------------
__global__ __launch_bounds__(256) void vq_split_kernel(const float* __restrict__ src,
                                                       f16* __restrict__ x16) {
  int i = (blockIdx.x * 256 + threadIdx.x) * 8;
  float4 v0 = *(const float4*)(src + i);
  float4 v1 = *(const float4*)(src + i + 4);
  float f[8] = {v0.x, v0.y, v0.z, v0.w, v1.x, v1.y, v1.z, v1.w};
  f16x8 h;
  #pragma unroll
  for (int j = 0; j < 8; ++j) h[j] = (f16)f[j];   // RNE, rel err <= 2^-11
  *(f16x8*)(x16 + i) = h;
}

// ---------------- kernel 1: emb fp16 cast + exact fp32 norms + counter zero ----------------
// one wave per code row: 64 lanes x 8 elems = 512
__global__ __launch_bounds__(256) void vq_split_enorm_kernel(
    const float* __restrict__ emb, f16* __restrict__ e16,
    float* __restrict__ enorm, int* __restrict__ rcounter) {
  int gid  = blockIdx.x * 256 + threadIdx.x;
  if (gid == 0) *rcounter = 0;
  int code = gid >> 6;
  int lane = gid & 63;
  size_t off = (size_t)code * DIM + lane * 8;
  float4 v0 = *(const float4*)(emb + off);
  float4 v1 = *(const float4*)(emb + off + 4);
  float f[8] = {v0.x, v0.y, v0.z, v0.w, v1.x, v1.y, v1.z, v1.w};
  f16x8 h;
  float s = 0.0f;
  #pragma unroll
  for (int j = 0; j < 8; ++j) {
    h[j] = (f16)f[j];
    s = fmaf(f[j], f[j], s);
  }
  *(f16x8*)(e16 + off) = h;
  #pragma unroll
  for (int o = 32; o > 0; o >>= 1) s += __shfl_down(s, o);
  if (lane == 0) enorm[code] = s;
}

// ---------------- async global->LDS 16B helper ----------------
__device__ __forceinline__ void gl2lds16(const f16* g, f16* l) {
  __builtin_amdgcn_global_load_lds((const __attribute__((address_space(1))) unsigned int*)g,
                                   (__attribute__((address_space(3))) unsigned int*)l,
                                   16, 0, 0);
}

__device__ __forceinline__ void top2_merge(float& d1, int& i1, float& d2,
                                           float od1, int oi1, float od2) {
  if (od1 < d1 || (od1 == d1 && oi1 < i1)) {
    d2 = fminf(d1, od2);
    d1 = od1; i1 = oi1;
  } else {
    d2 = fminf(d2, od1);
  }
}

// ---------------- kernel 2: single-term fp16 MFMA GEMM + top-2 argmin ----------------
// sim = x16.e16 (fp16 in, exact fp32 accumulate); dist = ||e||^2 - 2 sim.
// Rows with top-2 gap < MARGIN get exact fp32 refinement, so argmin is exact.
//
// Round-12: 256x128 tile, 8 waves (4 row-groups x 2 col-groups; each wave the
// SAME 64x64 sub-tile / 16 MFMA / 8 ds_read_b128 per K-step as the proven
// 4-wave kernel). Staging per K-step = 24KB for 2x the output of the old
// 16KB/128x128 block (0.75x staging per compute, 3 gl2lds/wave vs 4), and
// B-panel refetch halves. Sync skeleton UNCHANGED from the thrice-proven
// kernel: BK=32 double-buffer, stage-ahead, one __syncthreads per K-step
// (counted-vmcnt/raw-barrier variant is parked: R9 absmax 0.99 — raw
// s_barrier is not an IR-level memory fence).
// Reduction arrays ALIAS the dead A-tile LDS after the K-loop (post-barrier,
// no tile reads remain) -> 48KB total -> 3 blocks/CU if VGPR stays <=64-class.
// TN stays 128 so cand/merge2/rescan/gather are byte-identical to round 11.
//
// LDS tiles [rows][BK=32] f16; XOR swizzle (r0-proven, conflict-free, depends
// only on row mod 16): chunk fq of row r at slot fq ^ ((r>>1)&3); gl2lds
// writes linearly so the swizzle is realized source-side: lane l fetches
// chunk (l&3)^((l>>3)&3) of row l>>2 within each 16-row issue.
__global__ __launch_bounds__(512, 6) void vq_argmin_mfma_kernel(
    const f16* __restrict__ x16, const f16* __restrict__ e16,
    const float* __restrict__ enorm,
    float* __restrict__ cand_d1, int* __restrict__ cand_i1, float* __restrict__ cand_d2) {
  __shared__ __align__(16) char smem[49152];
  f16* Ab0 = (f16*)smem;                    // [256*32] 16 KB
  f16* Ab1 = (f16*)(smem + 16384);
  f16* Bb0 = (f16*)(smem + 32768);          // [128*32]  8 KB
  f16* Bb1 = (f16*)(smem + 40960);
  // post-K-loop aliases (A-tile region is dead then):
  float* red_d1 = (float*)smem;             // [2][256]
  int*   red_i1 = (int*)(smem + 2048);
  float* red_d2 = (float*)(smem + 4096);

  const int tid  = threadIdx.x;
  const int wave = tid >> 6;
  const int lane = tid & 63;
  const int bm = blockIdx.x, bn = blockIdx.y;
  const int wr = (wave >> 1) * 64;   // wave's row offset in 256-row tile
  const int wc = (wave & 1) * 64;    // wave's col offset in 128-col tile

  // staging: 24 16-row issues (0..15 = A rows, 16..23 = B rows); wave w owns
  // issues {3w, 3w+1, 3w+2}. Per issue: 64 lanes x 16B = 16 rows x 64B.
  const int srow = lane >> 2;                              // 0..15
  const int scg  = ((lane & 3) ^ ((lane >> 3) & 3)) * 8;   // swizzled chunk * 8 elems
  const f16* gs0; const f16* gs1; const f16* gs2;
  int doff0, doff1, doff2;
  bool ia0, ia1, ia2;
  {
    const int g0 = wave * 3, g1 = wave * 3 + 1, g2 = wave * 3 + 2;
    ia0 = g0 < 16; ia1 = g1 < 16; ia2 = g2 < 16;
    gs0 = ia0 ? x16 + (size_t)(bm * TM + g0 * 16 + srow) * DIM + scg
              : e16 + (size_t)(bn * TN + (g0 - 16) * 16 + srow) * DIM + scg;
    gs1 = ia1 ? x16 + (size_t)(bm * TM + g1 * 16 + srow) * DIM + scg
              : e16 + (size_t)(bn * TN + (g1 - 16) * 16 + srow) * DIM + scg;
    gs2 = ia2 ? x16 + (size_t)(bm * TM + g2 * 16 + srow) * DIM + scg
              : e16 + (size_t)(bn * TN + (g2 - 16) * 16 + srow) * DIM + scg;
    doff0 = (ia0 ? g0 : g0 - 16) * 16 * BK;
    doff1 = (ia1 ? g1 : g1 - 16) * 16 * BK;
    doff2 = (ia2 ? g2 : g2 - 16) * 16 * BK;
  }

  f32x4 acc[4][4];
  #pragma unroll
  for (int i = 0; i < 4; ++i)
    #pragma unroll
    for (int j = 0; j < 4; ++j)
      acc[i][j] = (f32x4){0.f, 0.f, 0.f, 0.f};

  const int fr = lane & 15;
  const int fq = lane >> 4;
  const int sw8 = (fq ^ ((fr >> 1) & 3)) * 8;

  // prologue: stage K-step 0 into buffer 0
  gl2lds16(gs0, (ia0 ? Ab0 : Bb0) + doff0);
  gl2lds16(gs1, (ia1 ? Ab0 : Bb0) + doff1);
  gl2lds16(gs2, (ia2 ? Ab0 : Bb0) + doff2);
  __syncthreads();   // vmcnt(0) drain: step-0 tiles resident

  #pragma unroll 2
  for (int s = 0; s < NT; ++s) {
    const int cur = s & 1;
    // stage-ahead: next K-step into the other buffer BEFORE compute.
    // Safe: buf^1's readers finished before the barrier ending step s-1.
    if (s + 1 < NT) {
      const int k1 = (s + 1) * BK;
      f16* An = cur ? Ab0 : Ab1;
      f16* Bn = cur ? Bb0 : Bb1;
      gl2lds16(gs0 + k1, (ia0 ? An : Bn) + doff0);
      gl2lds16(gs1 + k1, (ia1 ? An : Bn) + doff1);
      gl2lds16(gs2 + k1, (ia2 ? An : Bn) + doff2);
    }

    const f16* A = cur ? Ab1 : Ab0;
    const f16* B = cur ? Bb1 : Bb0;
    f16x8 a[4], b[4];
    #pragma unroll
    for (int f = 0; f < 4; ++f) {
      a[f] = *(const f16x8*)&A[(wr + f * 16 + fr) * BK + sw8];
      b[f] = *(const f16x8*)&B[(wc + f * 16 + fr) * BK + sw8];
    }
    #pragma unroll
    for (int mf = 0; mf < 4; ++mf)
      #pragma unroll
      for (int nf = 0; nf < 4; ++nf)
        acc[mf][nf] = __builtin_amdgcn_mfma_f32_16x16x32_f16(a[mf], b[nf], acc[mf][nf], 0, 0, 0);

    __syncthreads();   // drains stage-ahead loads (covered by compute) + joins waves
  }
  // From here on the LDS tiles are dead; red_* alias the A region (all tile
  // reads completed before the final barrier above).

  // ---- epilogue: distances + per-row top-2 over this block's 128 cols ----
  float en[4];
  #pragma unroll
  for (int nf = 0; nf < 4; ++nf)
    en[nf] = enorm[bn * TN + wc + nf * 16 + fr];

  #pragma unroll
  for (int mf = 0; mf < 4; ++mf) {
    #pragma unroll
    for (int reg = 0; reg < 4; ++reg) {
      float d1 = 3.4e38f, d2 = 3.4e38f;
      int i1 = 0;
      #pragma unroll
      for (int nf = 0; nf < 4; ++nf) {   // ascending col keeps lowest idx on ties
        float d = en[nf] - 2.0f * acc[mf][nf][reg];
        int ci = bn * TN + wc + nf * 16 + fr;
        if (d < d1) { d2 = d1; d1 = d; i1 = ci; }
        else if (d < d2) { d2 = d; }
      }
      // butterfly over the 16 lanes (same fq) holding this row's 64 cols
      #pragma unroll
      for (int m = 1; m <= 8; m <<= 1) {
        float od1 = __shfl_xor(d1, m, 16);
        int   oi1 = __shfl_xor(i1, m, 16);
        float od2 = __shfl_xor(d2, m, 16);
        top2_merge(d1, i1, d2, od1, oi1, od2);
      }
      if (fr == 0) {
        int row = wr + mf * 16 + fq * 4 + reg;   // [wr, wr+64)
        red_d1[(wave & 1) * TM + row] = d1;
        red_i1[(wave & 1) * TM + row] = i1;
        red_d2[(wave & 1) * TM + row] = d2;
      }
    }
  }
  __syncthreads();
  if (tid < TM) {
    float d1 = red_d1[tid]; int i1 = red_i1[tid]; float d2 = red_d2[tid];
    top2_merge(d1, i1, d2, red_d1[TM + tid], red_i1[TM + tid], red_d2[TM + tid]);
    size_t o = (size_t)bn * N_ROWS + (size_t)bm * TM + tid;
    cand_d1[o] = d1; cand_i1[o] = i1; cand_d2[o] = d2;
  }
}

// ---------------- kernel 3: merge 64 groups -> idx, flag + pruned rescan items ----------------
// For flagged rows (gap < MARGIN), emit (row, group) items only for groups
// whose stage-1 top-1 distance cd1_g <= d1 + MARGIN. Sufficiency: with
// per-distance error <= E = MARGIN/2 (the same bound the unflagged path
// relies on), the true argmin c* has comp(c*) <= d1 + 2E = d1 + MARGIN, so
// its group's cd1_g <= comp(c*) <= d1 + MARGIN and the group is scanned.
// The winner's own group always qualifies (cd1 = d1).
__global__ __launch_bounds__(256) void vq_merge2_kernel(
    const float* __restrict__ cd1, const int* __restrict__ ci1, const float* __restrict__ cd2,
    int* __restrict__ idx, int* __restrict__ flag,
    int* __restrict__ rcounter, int* __restrict__ item_row, int* __restrict__ item_grp,
    unsigned long long* __restrict__ packed,
    float* __restrict__ loss_slot) {
  int r = blockIdx.x * 256 + threadIdx.x;
  if (r == 0) *loss_slot = 0.0f;
  float d1 = 3.4e38f, d2 = 3.4e38f;
  int i1 = 0;
  for (int g = 0; g < NG; ++g) {   // ascending g = ascending col blocks
    size_t o = (size_t)g * N_ROWS + r;
    top2_merge(d1, i1, d2, cd1[o], ci1[o], cd2[o]);
  }
  idx[r] = i1;
  int f = (d2 - d1 < MARGIN) ? 1 : 0;
  flag[r] = f;
  if (f) {
    packed[r] = 0xFFFFFFFFFFFFFFFFULL;
    const float thresh = d1 + MARGIN;
    for (int g = 0; g < NG; ++g) {
      if (cd1[(size_t)g * N_ROWS + r] <= thresh) {
        int slot = atomicAdd(rcounter, 1);
        if (slot < CAP_ITEMS) { item_row[slot] = r; item_grp[slot] = g; }
      }
    }
  }
}

// ---------------- kernel 4: exact fp32 rescan of pruned (row, group) items ----------------
// One 128-thread block per item iteration: stage x row (2KB) in LDS, thread t
// computes the exact fp32 distance of code g*128+t (per-code arithmetic
// bit-identical to the verified round-0 rescan), wave-reduce packed u64 min,
// one atomicMin per item.
__global__ __launch_bounds__(128) void vq_rescan_kernel(
    const float* __restrict__ x, const float* __restrict__ emb,
    const float* __restrict__ enorm,
    const int* __restrict__ rcounter,
    const int* __restrict__ item_row, const int* __restrict__ item_grp,
    unsigned long long* __restrict__ packed) {
  __shared__ float4 xs[DIM / 4];            // 2 KB
  __shared__ unsigned long long wred[2];
  const int t = threadIdx.x;
  int nitems = rcounter[0];
  if (nitems > CAP_ITEMS) nitems = CAP_ITEMS;
  for (int item = blockIdx.x; item < nitems; item += gridDim.x) {
    const int r = item_row[item];
    const int g = item_grp[item];
    __syncthreads();   // protect xs from previous iteration's readers
    xs[t] = ((const float4*)(x + (size_t)r * DIM))[t];   // 128 x float4 = 512
    __syncthreads();
    const int c = g * 128 + t;
    const float4* e4 = (const float4*)(emb + (size_t)c * DIM);
    float s0 = 0.f, s1 = 0.f, s2 = 0.f, s3 = 0.f;
    for (int k = 0; k < DIM / 4; ++k) {
      float4 xv = xs[k]; float4 ev = e4[k];
      s0 = fmaf(xv.x, ev.x, s0); s1 = fmaf(xv.y, ev.y, s1);
      s2 = fmaf(xv.z, ev.z, s2); s3 = fmaf(xv.w, ev.w, s3);
    }
    float d = enorm[c] - 2.0f * ((s0 + s1) + (s2 + s3));
    unsigned long long p = pack_di(d, c);
    #pragma unroll
    for (int off = 32; off > 0; off >>= 1) {
      unsigned long long o = __shfl_down(p, off);
      if (o < p) p = o;
    }
    if ((t & 63) == 0) wred[t >> 6] = p;
    __syncthreads();
    if (t == 0) {
      unsigned long long m = wred[0];
      if (wred[1] < m) m = wred[1];
      atomicMin(&packed[r], m);
    }
  }
}

// ---------------- kernel 5: gather + outputs + loss ----------------
__global__ __launch_bounds__(256) void vq_gather_kernel(
    const float* __restrict__ x, const float* __restrict__ emb,
    const int* __restrict__ idx, const int* __restrict__ flag,
    const unsigned long long* __restrict__ packed,
    float* __restrict__ out, float* __restrict__ quant,
    float* __restrict__ loss_slot) {
  __shared__ float wsum[4];
  const int wave = threadIdx.x >> 6;
  const int lane = threadIdx.x & 63;
  const int row  = blockIdx.x * 4 + wave;
  const int code = flag[row] ? (int)(packed[row] & 0xFFFFFFFFu) : idx[row];
  const float4* xp = (const float4*)(x   + (size_t)row  * DIM + lane * 8);
  const float4* ep = (const float4*)(emb + (size_t)code * DIM + lane * 8);
  float s = 0.0f;
  #pragma unroll
  for (int t = 0; t < 2; ++t) {
    float4 xv = xp[t];
    float4 ev = ep[t];
    float dx = ev.x - xv.x, dy = ev.y - xv.y, dz = ev.z - xv.z, dw = ev.w - xv.w;
    s += dx * dx + dy * dy + dz * dz + dw * dw;
    ((float4*)(out   + (size_t)row * DIM + lane * 8))[t] = ev;  // out == quantized (straight-through)
    ((float4*)(quant + (size_t)row * DIM + lane * 8))[t] = ev;
  }
  #pragma unroll
  for (int off = 32; off > 0; off >>= 1) s += __shfl_down(s, off);
  if (lane == 0) wsum[wave] = s;
  __syncthreads();
  if (threadIdx.x == 0) {
    float tot = wsum[0] + wsum[1] + wsum[2] + wsum[3];
    atomicAdd(loss_slot, tot * (1.25f / (float)OUT_ELEMS));
  }
}

extern "C" void kernel_launch(void* const* d_in, const int* in_sizes, int n_in,
                              void* d_out, int out_size, void* d_ws, size_t ws_size,
                              hipStream_t stream) {
  const float* x   = (const float*)d_in[0];   // [16384, 512]
  const float* emb = (const float*)d_in[1];   // [8192, 512]
  float* out   = (float*)d_out;
  float* quant = out + OUT_ELEMS;
  float* loss  = out + 2 * OUT_ELEMS;

  char* ws = (char*)d_ws;
  f16*   x16    = (f16*)(ws);                           // 16.78 MB
  f16*   e16    = (f16*)(ws + 16777216);                //  8.39 MB
  float* enorm  = (float*)(ws + 25165824);              // 32 KB
  float* cd1    = (float*)(ws + 25198592);              // 4 MB
  int*   ci1    = (int*)  (ws + 29392896);              // 4 MB
  float* cd2    = (float*)(ws + 33587200);              // 4 MB
  int*   idx    = (int*)  (ws + 37781504);              // 64 KB
  int*   flag   = (int*)  (ws + 37847040);              // 64 KB
  int*   rcounter=(int*)  (ws + 37912576);              // 4 B (+pad)
  unsigned long long* packed = (unsigned long long*)(ws + 37912832); // 128 KB
  int*   item_row=(int*)  (ws + 38043904);              // 1 MB (262144 x 4)
  int*   item_grp=(int*)  (ws + 39092480);              // 1 MB

  vq_split_kernel<<<OUT_ELEMS / (8 * 256), 256, 0, stream>>>(x, x16);
  vq_split_enorm_kernel<<<K_CODES * 64 / 256, 256, 0, stream>>>(emb, e16, enorm, rcounter);
  vq_argmin_mfma_kernel<<<dim3(N_ROWS / TM, K_CODES / TN), 512, 0, stream>>>(
      x16, e16, enorm, cd1, ci1, cd2);
  vq_merge2_kernel<<<N_ROWS / 256, 256, 0, stream>>>(
      cd1, ci1, cd2, idx, flag, rcounter, item_row, item_grp, packed, loss);
  vq_rescan_kernel<<<2048, 128, 0, stream>>>(
      x, emb, enorm, rcounter, item_row, item_grp, packed);
  vq_gather_kernel<<<N_ROWS / 4, 256, 0, stream>>>(x, emb, idx, flag, packed, out, quant, loss);
}

// Round 13
// 434.231 us; speedup vs baseline: 2.9443x; 2.9443x over previous
//
#include <hip/hip_runtime.h>

#define DIM 512
#define N_ROWS 16384
#define K_CODES 8192
#define BK 32
#define TM 256
#define TN 128
#define NG (K_CODES / TN)               // 64 code groups
#define OUT_ELEMS (N_ROWS * DIM)        // 8388608
#define MARGIN 0.125f
#define CAP_ITEMS 262144                // (row,group) rescan items; ~3100 expected
#define NT (DIM / BK)                   // 16 K-steps

typedef _Float16 f16;
typedef _Float16 f16x8 __attribute__((ext_vector_type(8)));
typedef float f32x4 __attribute__((ext_vector_type(4)));

// monotone float->uint map: min on packed == (min dist, then min idx)
__device__ __forceinline__ unsigned long long pack_di(float d, int i) {
  unsigned u = __float_as_uint(d);
  u = (u & 0x80000000u) ? ~u : (u | 0x80000000u);
  return ((unsigned long long)u << 32) | (unsigned)i;
}

// ---------------- kernel 0: fp32 -> fp16 cast (x) ----------------
__global__ __launch_bounds__(256) void vq_split_kernel(const float* __restrict__ src,
                                                       f16* __restrict__ x16) {
  int i = (blockIdx.x * 256 + threadIdx.x) * 8;
  float4 v0 = *(const float4*)(src + i);
  float4 v1 = *(const float4*)(src + i + 4);
  float f[8] = {v0.x, v0.y, v0.z, v0.w, v1.x, v1.y, v1.z, v1.w};
  f16x8 h;
  #pragma unroll
  for (int j = 0; j < 8; ++j) h[j] = (f16)f[j];   // RNE, rel err <= 2^-11
  *(f16x8*)(x16 + i) = h;
}

// ---------------- kernel 1: emb fp16 cast + exact fp32 norms + counter zero ----------------
// one wave per code row: 64 lanes x 8 elems = 512
__global__ __launch_bounds__(256) void vq_split_enorm_kernel(
    const float* __restrict__ emb, f16* __restrict__ e16,
    float* __restrict__ enorm, int* __restrict__ rcounter) {
  int gid  = blockIdx.x * 256 + threadIdx.x;
  if (gid == 0) *rcounter = 0;
  int code = gid >> 6;
  int lane = gid & 63;
  size_t off = (size_t)code * DIM + lane * 8;
  float4 v0 = *(const float4*)(emb + off);
  float4 v1 = *(const float4*)(emb + off + 4);
  float f[8] = {v0.x, v0.y, v0.z, v0.w, v1.x, v1.y, v1.z, v1.w};
  f16x8 h;
  float s = 0.0f;
  #pragma unroll
  for (int j = 0; j < 8; ++j) {
    h[j] = (f16)f[j];
    s = fmaf(f[j], f[j], s);
  }
  *(f16x8*)(e16 + off) = h;
  #pragma unroll
  for (int o = 32; o > 0; o >>= 1) s += __shfl_down(s, o);
  if (lane == 0) enorm[code] = s;
}

// ---------------- async global->LDS 16B helper ----------------
__device__ __forceinline__ void gl2lds16(const f16* g, f16* l) {
  __builtin_amdgcn_global_load_lds((const __attribute__((address_space(1))) unsigned int*)g,
                                   (__attribute__((address_space(3))) unsigned int*)l,
                                   16, 0, 0);
}

__device__ __forceinline__ void top2_merge(float& d1, int& i1, float& d2,
                                           float od1, int oi1, float od2) {
  if (od1 < d1 || (od1 == d1 && oi1 < i1)) {
    d2 = fminf(d1, od2);
    d1 = od1; i1 = oi1;
  } else {
    d2 = fminf(d2, od1);
  }
}

// ---------------- kernel 2: single-term fp16 MFMA GEMM + top-2 argmin ----------------
// sim = x16.e16 (fp16 in, exact fp32 accumulate); dist = ||e||^2 - 2 sim.
// Rows with top-2 gap < MARGIN get exact fp32 refinement, so argmin is exact.
//
// Round-13: SAME 256x128/8-wave kernel as round 12 with ONE fix:
// __launch_bounds__(512, 2) instead of (512, 6). R12's (512,6) forced the
// allocator to 40 VGPRs -> acc[4][4] spilled to scratch (WRITE_SIZE 12MB ->
// 2.975GB, MfmaUtil 5.3%, 2.4x regression). With min-waves=2 the cap is 256;
// expected use ~110-130 -> 16 waves/CU (VGPR-bound), same wave count as the
// proven R11 config, but 0.75x staging volume and halved B-panel refetch.
// Sync skeleton UNCHANGED from the thrice-proven kernel: BK=32 double-buffer,
// stage-ahead, one __syncthreads per K-step (counted-vmcnt parked: R9).
// Reduction arrays alias the dead A-tile LDS after the K-loop.
// TN stays 128 so cand/merge2/rescan/gather are byte-identical to round 11.
//
// LDS tiles [rows][BK=32] f16; XOR swizzle (r0-proven, conflict-free, depends
// only on row mod 16): chunk fq of row r at slot fq ^ ((r>>1)&3); gl2lds
// writes linearly so the swizzle is realized source-side: lane l fetches
// chunk (l&3)^((l>>3)&3) of row l>>2 within each 16-row issue.
__global__ __launch_bounds__(512, 2) void vq_argmin_mfma_kernel(
    const f16* __restrict__ x16, const f16* __restrict__ e16,
    const float* __restrict__ enorm,
    float* __restrict__ cand_d1, int* __restrict__ cand_i1, float* __restrict__ cand_d2) {
  __shared__ __align__(16) char smem[49152];
  f16* Ab0 = (f16*)smem;                    // [256*32] 16 KB
  f16* Ab1 = (f16*)(smem + 16384);
  f16* Bb0 = (f16*)(smem + 32768);          // [128*32]  8 KB
  f16* Bb1 = (f16*)(smem + 40960);
  // post-K-loop aliases (A-tile region is dead then):
  float* red_d1 = (float*)smem;             // [2][256]
  int*   red_i1 = (int*)(smem + 2048);
  float* red_d2 = (float*)(smem + 4096);

  const int tid  = threadIdx.x;
  const int wave = tid >> 6;
  const int lane = tid & 63;
  const int bm = blockIdx.x, bn = blockIdx.y;
  const int wr = (wave >> 1) * 64;   // wave's row offset in 256-row tile
  const int wc = (wave & 1) * 64;    // wave's col offset in 128-col tile

  // staging: 24 16-row issues (0..15 = A rows, 16..23 = B rows); wave w owns
  // issues {3w, 3w+1, 3w+2}. Per issue: 64 lanes x 16B = 16 rows x 64B.
  const int srow = lane >> 2;                              // 0..15
  const int scg  = ((lane & 3) ^ ((lane >> 3) & 3)) * 8;   // swizzled chunk * 8 elems
  const f16* gs0; const f16* gs1; const f16* gs2;
  int doff0, doff1, doff2;
  bool ia0, ia1, ia2;
  {
    const int g0 = wave * 3, g1 = wave * 3 + 1, g2 = wave * 3 + 2;
    ia0 = g0 < 16; ia1 = g1 < 16; ia2 = g2 < 16;
    gs0 = ia0 ? x16 + (size_t)(bm * TM + g0 * 16 + srow) * DIM + scg
              : e16 + (size_t)(bn * TN + (g0 - 16) * 16 + srow) * DIM + scg;
    gs1 = ia1 ? x16 + (size_t)(bm * TM + g1 * 16 + srow) * DIM + scg
              : e16 + (size_t)(bn * TN + (g1 - 16) * 16 + srow) * DIM + scg;
    gs2 = ia2 ? x16 + (size_t)(bm * TM + g2 * 16 + srow) * DIM + scg
              : e16 + (size_t)(bn * TN + (g2 - 16) * 16 + srow) * DIM + scg;
    doff0 = (ia0 ? g0 : g0 - 16) * 16 * BK;
    doff1 = (ia1 ? g1 : g1 - 16) * 16 * BK;
    doff2 = (ia2 ? g2 : g2 - 16) * 16 * BK;
  }

  f32x4 acc[4][4];
  #pragma unroll
  for (int i = 0; i < 4; ++i)
    #pragma unroll
    for (int j = 0; j < 4; ++j)
      acc[i][j] = (f32x4){0.f, 0.f, 0.f, 0.f};

  const int fr = lane & 15;
  const int fq = lane >> 4;
  const int sw8 = (fq ^ ((fr >> 1) & 3)) * 8;

  // prologue: stage K-step 0 into buffer 0
  gl2lds16(gs0, (ia0 ? Ab0 : Bb0) + doff0);
  gl2lds16(gs1, (ia1 ? Ab0 : Bb0) + doff1);
  gl2lds16(gs2, (ia2 ? Ab0 : Bb0) + doff2);
  __syncthreads();   // vmcnt(0) drain: step-0 tiles resident

  #pragma unroll 2
  for (int s = 0; s < NT; ++s) {
    const int cur = s & 1;
    // stage-ahead: next K-step into the other buffer BEFORE compute.
    // Safe: buf^1's readers finished before the barrier ending step s-1.
    if (s + 1 < NT) {
      const int k1 = (s + 1) * BK;
      f16* An = cur ? Ab0 : Ab1;
      f16* Bn = cur ? Bb0 : Bb1;
      gl2lds16(gs0 + k1, (ia0 ? An : Bn) + doff0);
      gl2lds16(gs1 + k1, (ia1 ? An : Bn) + doff1);
      gl2lds16(gs2 + k1, (ia2 ? An : Bn) + doff2);
    }

    const f16* A = cur ? Ab1 : Ab0;
    const f16* B = cur ? Bb1 : Bb0;
    f16x8 a[4], b[4];
    #pragma unroll
    for (int f = 0; f < 4; ++f) {
      a[f] = *(const f16x8*)&A[(wr + f * 16 + fr) * BK + sw8];
      b[f] = *(const f16x8*)&B[(wc + f * 16 + fr) * BK + sw8];
    }
    #pragma unroll
    for (int mf = 0; mf < 4; ++mf)
      #pragma unroll
      for (int nf = 0; nf < 4; ++nf)
        acc[mf][nf] = __builtin_amdgcn_mfma_f32_16x16x32_f16(a[mf], b[nf], acc[mf][nf], 0, 0, 0);

    __syncthreads();   // drains stage-ahead loads (covered by compute) + joins waves
  }
  // From here on the LDS tiles are dead; red_* alias the A region (all tile
  // reads completed before the final barrier above).

  // ---- epilogue: distances + per-row top-2 over this block's 128 cols ----
  float en[4];
  #pragma unroll
  for (int nf = 0; nf < 4; ++nf)
    en[nf] = enorm[bn * TN + wc + nf * 16 + fr];

  #pragma unroll
  for (int mf = 0; mf < 4; ++mf) {
    #pragma unroll
    for (int reg = 0; reg < 4; ++reg) {
      float d1 = 3.4e38f, d2 = 3.4e38f;
      int i1 = 0;
      #pragma unroll
      for (int nf = 0; nf < 4; ++nf) {   // ascending col keeps lowest idx on ties
        float d = en[nf] - 2.0f * acc[mf][nf][reg];
        int ci = bn * TN + wc + nf * 16 + fr;
        if (d < d1) { d2 = d1; d1 = d; i1 = ci; }
        else if (d < d2) { d2 = d; }
      }
      // butterfly over the 16 lanes (same fq) holding this row's 64 cols
      #pragma unroll
      for (int m = 1; m <= 8; m <<= 1) {
        float od1 = __shfl_xor(d1, m, 16);
        int   oi1 = __shfl_xor(i1, m, 16);
        float od2 = __shfl_xor(d2, m, 16);
        top2_merge(d1, i1, d2, od1, oi1, od2);
      }
      if (fr == 0) {
        int row = wr + mf * 16 + fq * 4 + reg;   // [wr, wr+64)
        red_d1[(wave & 1) * TM + row] = d1;
        red_i1[(wave & 1) * TM + row] = i1;
        red_d2[(wave & 1) * TM + row] = d2;
      }
    }
  }
  __syncthreads();
  if (tid < TM) {
    float d1 = red_d1[tid]; int i1 = red_i1[tid]; float d2 = red_d2[tid];
    top2_merge(d1, i1, d2, red_d1[TM + tid], red_i1[TM + tid], red_d2[TM + tid]);
    size_t o = (size_t)bn * N_ROWS + (size_t)bm * TM + tid;
    cand_d1[o] = d1; cand_i1[o] = i1; cand_d2[o] = d2;
  }
}

// ---------------- kernel 3: merge 64 groups -> idx, flag + pruned rescan items ----------------
// For flagged rows (gap < MARGIN), emit (row, group) items only for groups
// whose stage-1 top-1 distance cd1_g <= d1 + MARGIN. Sufficiency: with
// per-distance error <= E = MARGIN/2 (the same bound the unflagged path
// relies on), the true argmin c* has comp(c*) <= d1 + 2E = d1 + MARGIN, so
// its group's cd1_g <= comp(c*) <= d1 + MARGIN and the group is scanned.
// The winner's own group always qualifies (cd1 = d1).
__global__ __launch_bounds__(256) void vq_merge2_kernel(
    const float* __restrict__ cd1, const int* __restrict__ ci1, const float* __restrict__ cd2,
    int* __restrict__ idx, int* __restrict__ flag,
    int* __restrict__ rcounter, int* __restrict__ item_row, int* __restrict__ item_grp,
    unsigned long long* __restrict__ packed,
    float* __restrict__ loss_slot) {
  int r = blockIdx.x * 256 + threadIdx.x;
  if (r == 0) *loss_slot = 0.0f;
  float d1 = 3.4e38f, d2 = 3.4e38f;
  int i1 = 0;
  for (int g = 0; g < NG; ++g) {   // ascending g = ascending col blocks
    size_t o = (size_t)g * N_ROWS + r;
    top2_merge(d1, i1, d2, cd1[o], ci1[o], cd2[o]);
  }
  idx[r] = i1;
  int f = (d2 - d1 < MARGIN) ? 1 : 0;
  flag[r] = f;
  if (f) {
    packed[r] = 0xFFFFFFFFFFFFFFFFULL;
    const float thresh = d1 + MARGIN;
    for (int g = 0; g < NG; ++g) {
      if (cd1[(size_t)g * N_ROWS + r] <= thresh) {
        int slot = atomicAdd(rcounter, 1);
        if (slot < CAP_ITEMS) { item_row[slot] = r; item_grp[slot] = g; }
      }
    }
  }
}

// ---------------- kernel 4: exact fp32 rescan of pruned (row, group) items ----------------
// One 128-thread block per item iteration: stage x row (2KB) in LDS, thread t
// computes the exact fp32 distance of code g*128+t (per-code arithmetic
// bit-identical to the verified round-0 rescan), wave-reduce packed u64 min,
// one atomicMin per item.
__global__ __launch_bounds__(128) void vq_rescan_kernel(
    const float* __restrict__ x, const float* __restrict__ emb,
    const float* __restrict__ enorm,
    const int* __restrict__ rcounter,
    const int* __restrict__ item_row, const int* __restrict__ item_grp,
    unsigned long long* __restrict__ packed) {
  __shared__ float4 xs[DIM / 4];            // 2 KB
  __shared__ unsigned long long wred[2];
  const int t = threadIdx.x;
  int nitems = rcounter[0];
  if (nitems > CAP_ITEMS) nitems = CAP_ITEMS;
  for (int item = blockIdx.x; item < nitems; item += gridDim.x) {
    const int r = item_row[item];
    const int g = item_grp[item];
    __syncthreads();   // protect xs from previous iteration's readers
    xs[t] = ((const float4*)(x + (size_t)r * DIM))[t];   // 128 x float4 = 512
    __syncthreads();
    const int c = g * 128 + t;
    const float4* e4 = (const float4*)(emb + (size_t)c * DIM);
    float s0 = 0.f, s1 = 0.f, s2 = 0.f, s3 = 0.f;
    for (int k = 0; k < DIM / 4; ++k) {
      float4 xv = xs[k]; float4 ev = e4[k];
      s0 = fmaf(xv.x, ev.x, s0); s1 = fmaf(xv.y, ev.y, s1);
      s2 = fmaf(xv.z, ev.z, s2); s3 = fmaf(xv.w, ev.w, s3);
    }
    float d = enorm[c] - 2.0f * ((s0 + s1) + (s2 + s3));
    unsigned long long p = pack_di(d, c);
    #pragma unroll
    for (int off = 32; off > 0; off >>= 1) {
      unsigned long long o = __shfl_down(p, off);
      if (o < p) p = o;
    }
    if ((t & 63) == 0) wred[t >> 6] = p;
    __syncthreads();
    if (t == 0) {
      unsigned long long m = wred[0];
      if (wred[1] < m) m = wred[1];
      atomicMin(&packed[r], m);
    }
  }
}

// ---------------- kernel 5: gather + outputs + loss ----------------
__global__ __launch_bounds__(256) void vq_gather_kernel(
    const float* __restrict__ x, const float* __restrict__ emb,
    const int* __restrict__ idx, const int* __restrict__ flag,
    const unsigned long long* __restrict__ packed,
    float* __restrict__ out, float* __restrict__ quant,
    float* __restrict__ loss_slot) {
  __shared__ float wsum[4];
  const int wave = threadIdx.x >> 6;
  const int lane = threadIdx.x & 63;
  const int row  = blockIdx.x * 4 + wave;
  const int code = flag[row] ? (int)(packed[row] & 0xFFFFFFFFu) : idx[row];
  const float4* xp = (const float4*)(x   + (size_t)row  * DIM + lane * 8);
  const float4* ep = (const float4*)(emb + (size_t)code * DIM + lane * 8);
  float s = 0.0f;
  #pragma unroll
  for (int t = 0; t < 2; ++t) {
    float4 xv = xp[t];
    float4 ev = ep[t];
    float dx = ev.x - xv.x, dy = ev.y - xv.y, dz = ev.z - xv.z, dw = ev.w - xv.w;
    s += dx * dx + dy * dy + dz * dz + dw * dw;
    ((float4*)(out   + (size_t)row * DIM + lane * 8))[t] = ev;  // out == quantized (straight-through)
    ((float4*)(quant + (size_t)row * DIM + lane * 8))[t] = ev;
  }
  #pragma unroll
  for (int off = 32; off > 0; off >>= 1) s += __shfl_down(s, off);
  if (lane == 0) wsum[wave] = s;
  __syncthreads();
  if (threadIdx.x == 0) {
    float tot = wsum[0] + wsum[1] + wsum[2] + wsum[3];
    atomicAdd(loss_slot, tot * (1.25f / (float)OUT_ELEMS));
  }
}

extern "C" void kernel_launch(void* const* d_in, const int* in_sizes, int n_in,
                              void* d_out, int out_size, void* d_ws, size_t ws_size,
                              hipStream_t stream) {
  const float* x   = (const float*)d_in[0];   // [16384, 512]
  const float* emb = (const float*)d_in[1];   // [8192, 512]
  float* out   = (float*)d_out;
  float* quant = out + OUT_ELEMS;
  float* loss  = out + 2 * OUT_ELEMS;

  char* ws = (char*)d_ws;
  f16*   x16    = (f16*)(ws);                           // 16.78 MB
  f16*   e16    = (f16*)(ws + 16777216);                //  8.39 MB
  float* enorm  = (float*)(ws + 25165824);              // 32 KB
  float* cd1    = (float*)(ws + 25198592);              // 4 MB
  int*   ci1    = (int*)  (ws + 29392896);              // 4 MB
  float* cd2    = (float*)(ws + 33587200);              // 4 MB
  int*   idx    = (int*)  (ws + 37781504);              // 64 KB
  int*   flag   = (int*)  (ws + 37847040);              // 64 KB
  int*   rcounter=(int*)  (ws + 37912576);              // 4 B (+pad)
  unsigned long long* packed = (unsigned long long*)(ws + 37912832); // 128 KB
  int*   item_row=(int*)  (ws + 38043904);              // 1 MB (262144 x 4)
  int*   item_grp=(int*)  (ws + 39092480);              // 1 MB

  vq_split_kernel<<<OUT_ELEMS / (8 * 256), 256, 0, stream>>>(x, x16);
  vq_split_enorm_kernel<<<K_CODES * 64 / 256, 256, 0, stream>>>(emb, e16, enorm, rcounter);
  vq_argmin_mfma_kernel<<<dim3(N_ROWS / TM, K_CODES / TN), 512, 0, stream>>>(
      x16, e16, enorm, cd1, ci1, cd2);
  vq_merge2_kernel<<<N_ROWS / 256, 256, 0, stream>>>(
      cd1, ci1, cd2, idx, flag, rcounter, item_row, item_grp, packed, loss);
  vq_rescan_kernel<<<2048, 128, 0, stream>>>(
      x, emb, enorm, rcounter, item_row, item_grp, packed);
  vq_gather_kernel<<<N_ROWS / 4, 256, 0, stream>>>(x, emb, idx, flag, packed, out, quant, loss);
}